// Round 1
// 109.798 us; speedup vs baseline: 1.0321x; 1.0321x over previous
//
#include <hip/hip_runtime.h>

// GenomeNet: B=4096, N_IN=W=N_OUT=1024, L=8 hidden, D=16 fan-in.
// R7: TB=16 batch tile with lane-pair-split rows.
//  - 256 blocks x 1024 threads; each block owns 16 batch elements.
//  - LDS rows are 32 B fp16 ([node][16 batch]); thread pair (2k,2k+1)
//    handles one node, each thread gathers the 16 B half-row for its own
//    8 batch elements: addr = 32*si + 16*(t&1).
//    Even lanes -> bank groups {0,8,16,24}, odd -> {4,12,20,28}:
//    two disjoint multinomial(32,4) loads instead of multinomial(64,8)
//    => conflict ratio ~2.0x -> ~1.4x.
//  - Weight/index (src,w) L2 traffic per batch element is HALVED vs TB=8
//    (128 KB/node-set/layer amortized over 16 batches instead of 8).
//  - launch_bounds(1024,4): 128 VGPR budget so the 8-deep ds_read_b128
//    pipeline can stay in flight (R6's ",8" bound strangled it at 32).
//  - 1024 nodes / 512 pairs => 2 passes per layer; LDS writes stay
//    deterministically conflict-free (8 lanes per quad-group per instr).

#define TB       16
#define W_NODES  1024
#define LAYERS   8
#define ROW_H    16                    // halfs per node row (32 B)
#define BUF_H    (W_NODES * ROW_H)     // 16384 halfs = 32 KB

typedef _Float16 h8 __attribute__((ext_vector_type(8)));

__device__ __forceinline__ float fast_tanh(float x) {
    // tanh(x) = 1 - 2/(e^{2x}+1)
    float a = __builtin_amdgcn_exp2f(x * 2.8853900817779268f);
    return 1.0f - 2.0f * __builtin_amdgcn_rcpf(a + 1.0f);
}

// Gather 16 half-rows (16 B each) for one node with a software pipeline.
// hfo = half-offset in halfs (0 or 8). Accumulates this thread's 8 batches.
__device__ __forceinline__ void gather16_half(const _Float16* __restrict__ rd,
                                              const int* __restrict__ si,
                                              const float* __restrict__ wi,
                                              const int hfo,
                                              float* __restrict__ acc)
{
#define LDV(i) (*(const h8*)(rd + ((si[i] << 4) + hfo)))
#define FMA8(g, w)                                        \
    do {                                                  \
        const float _w = (w);                             \
        _Pragma("unroll")                                 \
        for (int j = 0; j < 8; ++j)                       \
            acc[j] = fmaf((float)(g)[j], _w, acc[j]);     \
    } while (0)

    h8 g0 = LDV(0);  h8 g1 = LDV(1);  h8 g2 = LDV(2);  h8 g3 = LDV(3);
    h8 g4 = LDV(4);  h8 g5 = LDV(5);  h8 g6 = LDV(6);  h8 g7 = LDV(7);

    FMA8(g0, wi[0]);  FMA8(g1, wi[1]);
    g0 = LDV(8);      g1 = LDV(9);
    FMA8(g2, wi[2]);  FMA8(g3, wi[3]);
    g2 = LDV(10);     g3 = LDV(11);
    FMA8(g4, wi[4]);  FMA8(g5, wi[5]);
    g4 = LDV(12);     g5 = LDV(13);
    FMA8(g6, wi[6]);  FMA8(g7, wi[7]);
    g6 = LDV(14);     g7 = LDV(15);

    FMA8(g0, wi[8]);  FMA8(g1, wi[9]);
    FMA8(g2, wi[10]); FMA8(g3, wi[11]);
    FMA8(g4, wi[12]); FMA8(g5, wi[13]);
    FMA8(g6, wi[14]); FMA8(g7, wi[15]);
#undef LDV
#undef FMA8
}

__global__ __launch_bounds__(1024, 4) void genome_net(
    const float* __restrict__ x,
    const int*   __restrict__ src_hidden,
    const float* __restrict__ w_hidden,
    const int*   __restrict__ src_out,
    const float* __restrict__ w_out,
    float*       __restrict__ out)
{
    extern __shared__ _Float16 lds[];
    _Float16* bufA = lds;              // [1024 nodes][16 batch] fp16, 32 KB
    _Float16* bufB = lds + BUF_H;

    const int t   = threadIdx.x;
    const int pr  = t >> 1;            // pair index 0..511
    const int hf  = t & 1;             // which 16 B half of the row
    const int hfo = hf << 3;           // half offset in halfs
    const int b0  = blockIdx.x * TB;
    const int bb  = b0 + hfo;          // this thread's 8-batch base

    // ---- Stage x: fp32 -> fp16 half-rows, 2 node passes.
    // For fixed (p,j): even lanes read batch bb+j nodes 0..31 (+512p) =
    // contiguous 128 B; odd lanes the same for batch bb+8+j. Coalesced.
    #pragma unroll
    for (int p = 0; p < 2; ++p) {
        const int n = (p << 9) + pr;
        h8 hv;
        #pragma unroll
        for (int j = 0; j < 8; ++j)
            hv[j] = (_Float16)x[(size_t)(bb + j) * W_NODES + n];
        *(h8*)(bufA + n * ROW_H + hfo) = hv;   // 8 lanes/quad-group: clean
    }
    __syncthreads();

    _Float16* rd = bufA;
    _Float16* wr = bufB;

    #pragma unroll 1
    for (int l = 0; l < LAYERS; ++l) {
        #pragma unroll
        for (int p = 0; p < 2; ++p) {
            const int n   = (p << 9) + pr;
            const int row = (l << 10) + n;
            const int4*   sp = (const int4*)(src_hidden) + (row << 2);
            const float4* wp = (const float4*)(w_hidden) + (row << 2);
            int4   s4[4]; float4 w4[4];
            #pragma unroll
            for (int q = 0; q < 4; ++q) { s4[q] = sp[q]; w4[q] = wp[q]; }
            int   si[16]; float wi[16];
            #pragma unroll
            for (int q = 0; q < 4; ++q) {
                si[4*q+0] = s4[q].x; si[4*q+1] = s4[q].y;
                si[4*q+2] = s4[q].z; si[4*q+3] = s4[q].w;
                wi[4*q+0] = w4[q].x; wi[4*q+1] = w4[q].y;
                wi[4*q+2] = w4[q].z; wi[4*q+3] = w4[q].w;
            }

            float acc[8];
            #pragma unroll
            for (int j = 0; j < 8; ++j) acc[j] = 0.0f;

            gather16_half(rd, si, wi, hfo, acc);

            h8 hv;
            #pragma unroll
            for (int j = 0; j < 8; ++j) hv[j] = (_Float16)fast_tanh(acc[j]);
            *(h8*)(wr + n * ROW_H + hfo) = hv;  // 8 lanes/quad-group: clean
        }

        __syncthreads();
        _Float16* tmp = rd; rd = wr; wr = tmp;
    }

    // ---- Output layer: identity activation, fp32 accumulate + stores.
    #pragma unroll
    for (int p = 0; p < 2; ++p) {
        const int n = (p << 9) + pr;
        const int4*   sp = (const int4*)(src_out) + (n << 2);
        const float4* wp = (const float4*)(w_out) + (n << 2);
        int4   s4[4]; float4 w4[4];
        #pragma unroll
        for (int q = 0; q < 4; ++q) { s4[q] = sp[q]; w4[q] = wp[q]; }
        int   si[16]; float wi[16];
        #pragma unroll
        for (int q = 0; q < 4; ++q) {
            si[4*q+0] = s4[q].x; si[4*q+1] = s4[q].y;
            si[4*q+2] = s4[q].z; si[4*q+3] = s4[q].w;
            wi[4*q+0] = w4[q].x; wi[4*q+1] = w4[q].y;
            wi[4*q+2] = w4[q].z; wi[4*q+3] = w4[q].w;
        }

        float acc[8];
        #pragma unroll
        for (int j = 0; j < 8; ++j) acc[j] = 0.0f;

        gather16_half(rd, si, wi, hfo, acc);

        // For fixed j: even lanes write batch bb+j nodes 0..31 (+512p),
        // contiguous 128 B; odd lanes batch bb+8+j. Coalesced.
        #pragma unroll
        for (int j = 0; j < 8; ++j)
            out[(size_t)(bb + j) * W_NODES + n] = acc[j];
    }
}

extern "C" void kernel_launch(void* const* d_in, const int* in_sizes, int n_in,
                              void* d_out, int out_size, void* d_ws, size_t ws_size,
                              hipStream_t stream) {
    const float* x  = (const float*)d_in[0];
    const int*   sh = (const int*)  d_in[1];
    const float* wh = (const float*)d_in[2];
    const int*   so = (const int*)  d_in[3];
    const float* wo = (const float*)d_in[4];
    float* out = (float*)d_out;

    const int shmem = 2 * BUF_H * (int)sizeof(_Float16);   // 65536 B
    hipFuncSetAttribute(reinterpret_cast<const void*>(genome_net),
                        hipFuncAttributeMaxDynamicSharedMemorySize, shmem);

    genome_net<<<dim3(4096 / TB), dim3(1024), shmem, stream>>>(
        x, sh, wh, so, wo, out);
}

// Round 2
// 109.014 us; speedup vs baseline: 1.0395x; 1.0072x over previous
//
#include <hip/hip_runtime.h>

// GenomeNet: B=4096, N_IN=W=N_OUT=1024, L=8 hidden, D=16 fan-in.
// R8: R7 structure (TB=16, lane-pair-split 32B rows, 8-deep ds_read
// pipeline) + inline-asm v_fma_mix_f32 inner loop.
//   R7 post-mortem: VALUBusy accounting shows the compiler emitted
//   v_cvt_f16_f32 + v_fma_f32 per element (256 VALU instr/pass) instead of
//   v_fma_mix_f32 (128/pass). VALU (~6k cyc/SIMD/layer) was co-dominant
//   with the LDS gather pipe (~7.3k cyc/CU/layer) and they serialized.
//   fma_mix halves VALU with bit-identical numerics (fp16 operand is
//   promoted inside the FMA; weight stays fp32).

#define TB       16
#define W_NODES  1024
#define LAYERS   8
#define ROW_H    16                    // halfs per node row (32 B)
#define BUF_H    (W_NODES * ROW_H)     // 16384 halfs = 32 KB

typedef _Float16 h8   __attribute__((ext_vector_type(8)));
typedef unsigned int u32x4 __attribute__((ext_vector_type(4)));

__device__ __forceinline__ float fast_tanh(float x) {
    // tanh(x) = 1 - 2/(e^{2x}+1)
    float a = __builtin_amdgcn_exp2f(x * 2.8853900817779268f);
    return 1.0f - 2.0f * __builtin_amdgcn_rcpf(a + 1.0f);
}

// Gather 16 half-rows (16 B each) for one node with a software pipeline.
// hfo = half-offset in halfs (0 or 8). Accumulates this thread's 8 batches.
// Inner op: v_fma_mix_f32 — fp16 source (lo/hi half of g word) * fp32 w
// + fp32 acc, one instruction per (edge, batch).
__device__ __forceinline__ void gather16_half(const _Float16* __restrict__ rd,
                                              const int* __restrict__ si,
                                              const float* __restrict__ wi,
                                              const int hfo,
                                              float* __restrict__ acc)
{
#define LDV(i) (*(const h8*)(rd + ((si[i] << 4) + hfo)))
#define FMA8(g, w)                                                          \
    do {                                                                    \
        const float _w = (w);                                               \
        const u32x4 _gw = __builtin_bit_cast(u32x4, (g));                   \
        _Pragma("unroll")                                                   \
        for (int k = 0; k < 4; ++k) {                                       \
            asm("v_fma_mix_f32 %0, %1, %2, %0 op_sel:[0,0,0] op_sel_hi:[1,0,0]" \
                : "+v"(acc[2 * k + 0]) : "v"(_gw[k]), "v"(_w));             \
            asm("v_fma_mix_f32 %0, %1, %2, %0 op_sel:[1,0,0] op_sel_hi:[1,0,0]" \
                : "+v"(acc[2 * k + 1]) : "v"(_gw[k]), "v"(_w));             \
        }                                                                   \
    } while (0)

    h8 g0 = LDV(0);  h8 g1 = LDV(1);  h8 g2 = LDV(2);  h8 g3 = LDV(3);
    h8 g4 = LDV(4);  h8 g5 = LDV(5);  h8 g6 = LDV(6);  h8 g7 = LDV(7);

    FMA8(g0, wi[0]);  FMA8(g1, wi[1]);
    g0 = LDV(8);      g1 = LDV(9);
    FMA8(g2, wi[2]);  FMA8(g3, wi[3]);
    g2 = LDV(10);     g3 = LDV(11);
    FMA8(g4, wi[4]);  FMA8(g5, wi[5]);
    g4 = LDV(12);     g5 = LDV(13);
    FMA8(g6, wi[6]);  FMA8(g7, wi[7]);
    g6 = LDV(14);     g7 = LDV(15);

    FMA8(g0, wi[8]);  FMA8(g1, wi[9]);
    FMA8(g2, wi[10]); FMA8(g3, wi[11]);
    FMA8(g4, wi[12]); FMA8(g5, wi[13]);
    FMA8(g6, wi[14]); FMA8(g7, wi[15]);
#undef LDV
#undef FMA8
}

__global__ __launch_bounds__(1024, 4) void genome_net(
    const float* __restrict__ x,
    const int*   __restrict__ src_hidden,
    const float* __restrict__ w_hidden,
    const int*   __restrict__ src_out,
    const float* __restrict__ w_out,
    float*       __restrict__ out)
{
    extern __shared__ _Float16 lds[];
    _Float16* bufA = lds;              // [1024 nodes][16 batch] fp16, 32 KB
    _Float16* bufB = lds + BUF_H;

    const int t   = threadIdx.x;
    const int pr  = t >> 1;            // pair index 0..511
    const int hf  = t & 1;             // which 16 B half of the row
    const int hfo = hf << 3;           // half offset in halfs
    const int b0  = blockIdx.x * TB;
    const int bb  = b0 + hfo;          // this thread's 8-batch base

    // ---- Stage x: fp32 -> fp16 half-rows, 2 node passes. Coalesced.
    #pragma unroll
    for (int p = 0; p < 2; ++p) {
        const int n = (p << 9) + pr;
        h8 hv;
        #pragma unroll
        for (int j = 0; j < 8; ++j)
            hv[j] = (_Float16)x[(size_t)(bb + j) * W_NODES + n];
        *(h8*)(bufA + n * ROW_H + hfo) = hv;   // 8 lanes/quad-group: clean
    }
    __syncthreads();

    _Float16* rd = bufA;
    _Float16* wr = bufB;

    #pragma unroll 1
    for (int l = 0; l < LAYERS; ++l) {
        #pragma unroll
        for (int p = 0; p < 2; ++p) {
            const int n   = (p << 9) + pr;
            const int row = (l << 10) + n;
            const int4*   sp = (const int4*)(src_hidden) + (row << 2);
            const float4* wp = (const float4*)(w_hidden) + (row << 2);
            int4   s4[4]; float4 w4[4];
            #pragma unroll
            for (int q = 0; q < 4; ++q) { s4[q] = sp[q]; w4[q] = wp[q]; }
            int   si[16]; float wi[16];
            #pragma unroll
            for (int q = 0; q < 4; ++q) {
                si[4*q+0] = s4[q].x; si[4*q+1] = s4[q].y;
                si[4*q+2] = s4[q].z; si[4*q+3] = s4[q].w;
                wi[4*q+0] = w4[q].x; wi[4*q+1] = w4[q].y;
                wi[4*q+2] = w4[q].z; wi[4*q+3] = w4[q].w;
            }

            float acc[8];
            #pragma unroll
            for (int j = 0; j < 8; ++j) acc[j] = 0.0f;

            gather16_half(rd, si, wi, hfo, acc);

            h8 hv;
            #pragma unroll
            for (int j = 0; j < 8; ++j) hv[j] = (_Float16)fast_tanh(acc[j]);
            *(h8*)(wr + n * ROW_H + hfo) = hv;  // 8 lanes/quad-group: clean
        }

        __syncthreads();
        _Float16* tmp = rd; rd = wr; wr = tmp;
    }

    // ---- Output layer: identity activation, fp32 accumulate + stores.
    #pragma unroll
    for (int p = 0; p < 2; ++p) {
        const int n = (p << 9) + pr;
        const int4*   sp = (const int4*)(src_out) + (n << 2);
        const float4* wp = (const float4*)(w_out) + (n << 2);
        int4   s4[4]; float4 w4[4];
        #pragma unroll
        for (int q = 0; q < 4; ++q) { s4[q] = sp[q]; w4[q] = wp[q]; }
        int   si[16]; float wi[16];
        #pragma unroll
        for (int q = 0; q < 4; ++q) {
            si[4*q+0] = s4[q].x; si[4*q+1] = s4[q].y;
            si[4*q+2] = s4[q].z; si[4*q+3] = s4[q].w;
            wi[4*q+0] = w4[q].x; wi[4*q+1] = w4[q].y;
            wi[4*q+2] = w4[q].z; wi[4*q+3] = w4[q].w;
        }

        float acc[8];
        #pragma unroll
        for (int j = 0; j < 8; ++j) acc[j] = 0.0f;

        gather16_half(rd, si, wi, hfo, acc);

        // Coalesced: fixed j -> even lanes contiguous 128 B, odd likewise.
        #pragma unroll
        for (int j = 0; j < 8; ++j)
            out[(size_t)(bb + j) * W_NODES + n] = acc[j];
    }
}

extern "C" void kernel_launch(void* const* d_in, const int* in_sizes, int n_in,
                              void* d_out, int out_size, void* d_ws, size_t ws_size,
                              hipStream_t stream) {
    const float* x  = (const float*)d_in[0];
    const int*   sh = (const int*)  d_in[1];
    const float* wh = (const float*)d_in[2];
    const int*   so = (const int*)  d_in[3];
    const float* wo = (const float*)d_in[4];
    float* out = (float*)d_out;

    const int shmem = 2 * BUF_H * (int)sizeof(_Float16);   // 65536 B
    hipFuncSetAttribute(reinterpret_cast<const void*>(genome_net),
                        hipFuncAttributeMaxDynamicSharedMemorySize, shmem);

    genome_net<<<dim3(4096 / TB), dim3(1024), shmem, stream>>>(
        x, sh, wh, so, wo, out);
}